// Round 5
// baseline (530.358 us; speedup 1.0000x reference)
//
#include <hip/hip_runtime.h>
#include <hip/hip_bf16.h>
#include <stdint.h>

// Router: logits = x @ wg^T + gr @ gm^T ; std-normalized softmax; top-2;
// zero expert 7; renormalize. Outputs flat: gates[T,2] | indices[T,2] (as
// float) | logits[T,8].  T=16384, D=2048, E=8.
//
// R5: split-K two-kernel, REGISTER-PRESSURE-SAFE.
//  Theory: R1-R4 all ran 60-90us regardless of structure because peak VGPR
//  demand sat at/over the launch_bounds cap -> scratch spill traffic
//  (R3's 26MB WRITE_SIZE was the visible case). R5 halves the accumulator:
//  4-token batches, acc[32], butterfly over 32 values per 32-lane half +
//  one xor-32 fold. Peak live = 32 acc + 32 wg + 32 xbuf + ~15 temps
//  ~= 111 VGPR vs cap 168 -> guaranteed no spill.
//  Kernel 1: wave owns (column-group of 256 cols, 32 tokens); wg slice in
//    regs (loaded once); NO LDS, NO barriers. Per batch: 4x 1KB coalesced
//    x-loads (ping-pong), 128 fmacs, 5-stage butterfly + fold, 128B store.
//  Kernel 2: lane sums 8 column-group partials, then proven epilogue.

#define DCONST 2048

__device__ __forceinline__ unsigned long long shfl_xor_u64(unsigned long long v, int m) {
    int lo = __shfl_xor((int)(uint32_t)v, m, 64);
    int hi = __shfl_xor((int)(uint32_t)(v >> 32), m, 64);
    return ((unsigned long long)(uint32_t)hi << 32) | (unsigned long long)(uint32_t)lo;
}

// ---------------- Kernel 1: split-K partial GEMM ----------------
__global__ __launch_bounds__(256, 3)
void router_gemm(const float* __restrict__ x,   // [T,2048]
                 const float* __restrict__ wg,  // [8,2048]
                 float* __restrict__ ws,        // [T/8][8][64] partials
                 int T)
{
    const int wave  = threadIdx.x >> 6;
    const int lane  = threadIdx.x & 63;
    const int W     = blockIdx.x * 4 + wave;
    const int g     = W & 7;                 // column group (256 cols)
    const int tbase = (W >> 3) * 32;         // first of 32 tokens
    const int tb0   = tbase >> 3;            // first 8-token block id

    // wg slice for this lane's 4 columns, all 8 experts: 32 VGPRs, once.
    const float* wgp = wg + g * 256 + (lane << 2);
    float4 w8[8];
    #pragma unroll
    for (int e = 0; e < 8; ++e)
        w8[e] = *(const float4*)(wgp + (size_t)e * DCONST);

    const float* xp = x + (size_t)tbase * DCONST + g * 256 + (lane << 2);

    float4 xa[4], xb[4];
    float acc[32];

    #define LOADQ(buf, b)                                                     \
        { _Pragma("unroll")                                                   \
          for (int i = 0; i < 4; ++i)                                         \
              buf[i] = *(const float4*)(xp + (size_t)((b) * 4 + i) * DCONST); }

    #define BATCH(buf)                                                        \
        { _Pragma("unroll")                                                   \
          for (int v = 0; v < 32; ++v) acc[v] = 0.f;                          \
          _Pragma("unroll")                                                   \
          for (int i = 0; i < 4; ++i) {                                       \
              _Pragma("unroll")                                               \
              for (int e = 0; e < 8; ++e) {                                   \
                  float a = acc[i * 8 + e];                                   \
                  a += buf[i].x * w8[e].x;                                    \
                  a += buf[i].y * w8[e].y;                                    \
                  a += buf[i].z * w8[e].z;                                    \
                  a += buf[i].w * w8[e].w;                                    \
                  acc[i * 8 + e] = a;                                         \
              }                                                               \
          } }

    // 5-stage butterfly reduce-scatter within each 32-lane half, then
    // xor-32 fold (halves cover different column sub-ranges). Lane l ends
    // with value l&31 fully summed over this wave's 256 columns.
    #define RED(b)                                                            \
        { _Pragma("unroll")                                                   \
          for (int m = 1; m < 32; m <<= 1) {                                  \
              const bool up = (lane & m) != 0;                                \
              _Pragma("unroll")                                               \
              for (int v = 0; v < 32; v += 2 * m) {                           \
                  const float keep = up ? acc[v + m] : acc[v];                \
                  const float send = up ? acc[v] : acc[v + m];                \
                  const float got  = __shfl_xor(send, m, 64);                 \
                  acc[v] = keep + got;                                        \
              }                                                               \
          }                                                                   \
          const float r = acc[0] + __shfl_xor(acc[0], 32, 64);                \
          if (lane < 32)                                                      \
              ws[(size_t)(tb0 + ((b) >> 1)) * 512 + g * 64                    \
                 + ((b) & 1) * 32 + lane] = r; }

    LOADQ(xa, 0); LOADQ(xb, 1);
    BATCH(xa); LOADQ(xa, 2); RED(0);
    BATCH(xb); LOADQ(xb, 3); RED(1);
    BATCH(xa); LOADQ(xa, 4); RED(2);
    BATCH(xb); LOADQ(xb, 5); RED(3);
    BATCH(xa); LOADQ(xa, 6); RED(4);
    BATCH(xb); LOADQ(xb, 7); RED(5);
    BATCH(xa); RED(6);
    BATCH(xb); RED(7);
}

// ---------------- Kernel 2: reduce + epilogue ----------------
__global__ __launch_bounds__(256)
void router_epilogue(const float* __restrict__ ws,  // [T/8][8][64]
                     const float* __restrict__ gm,  // [8,8]
                     const float* __restrict__ gr,  // [T,8]
                     float* __restrict__ out,       // 2T gates | 2T idx | 8T logits
                     int T)
{
    const int wave = threadIdx.x >> 6;
    const int lane = threadIdx.x & 63;
    const int tb   = blockIdx.x * 4 + wave;    // [0, T/8)
    const int t0   = tb * 8;

    float logit = 0.f;
    #pragma unroll
    for (int g = 0; g < 8; ++g)
        logit += ws[(size_t)tb * 512 + g * 64 + lane];

    const int tt = lane >> 3;
    const int f  = lane & 7;
    const int t  = t0 + tt;

    // residual: logit += sum_e gr[t][e] * gm[f][e]
    const float4 ga = *(const float4*)(gr + (size_t)t * 8);
    const float4 gb = *(const float4*)(gr + (size_t)t * 8 + 4);
    const float4 ma = *(const float4*)(gm + f * 8);
    const float4 mb = *(const float4*)(gm + f * 8 + 4);
    logit += ga.x * ma.x + ga.y * ma.y + ga.z * ma.z + ga.w * ma.w
           + gb.x * mb.x + gb.y * mb.y + gb.z * mb.z + gb.w * mb.w;

    // logits output (offset 4T), contiguous per wave
    out[(size_t)4 * T + (size_t)t0 * 8 + lane] = logit;

    // stats over the 8-lane expert group
    float s = logit;
    s += __shfl_xor(s, 1, 64);
    s += __shfl_xor(s, 2, 64);
    s += __shfl_xor(s, 4, 64);
    const float mean = s * 0.125f;
    float d2 = (logit - mean) * (logit - mean);
    d2 += __shfl_xor(d2, 1, 64);
    d2 += __shfl_xor(d2, 2, 64);
    d2 += __shfl_xor(d2, 4, 64);
    const float stdv = sqrtf(d2 / 7.0f);    // ddof=1

    // top-2 via order-preserving 64-bit keys; ties -> smaller index
    uint32_t ob = __float_as_uint(logit);
    ob = (ob & 0x80000000u) ? ~ob : (ob | 0x80000000u);
    unsigned long long k1 = ((unsigned long long)ob << 8) | (unsigned long long)(7 - f);
    unsigned long long k2 = 0ull;
    #pragma unroll
    for (int m = 1; m <= 4; m <<= 1) {
        const unsigned long long o1 = shfl_xor_u64(k1, m);
        const unsigned long long o2 = shfl_xor_u64(k2, m);
        const unsigned long long hi = k1 > o1 ? k1 : o1;
        const unsigned long long lo = k1 > o1 ? o1 : k1;
        const unsigned long long so = k2 > o2 ? k2 : o2;
        k1 = hi;
        k2 = lo > so ? lo : so;
    }
    const int i1 = 7 - (int)(k1 & 0xFFull);
    const int i2 = 7 - (int)(k2 & 0xFFull);
    uint32_t b1 = (uint32_t)(k1 >> 8), b2 = (uint32_t)(k2 >> 8);
    b1 = (b1 & 0x80000000u) ? (b1 ^ 0x80000000u) : ~b1;
    b2 = (b2 & 0x80000000u) ? (b2 ^ 0x80000000u) : ~b2;
    const float l1 = __uint_as_float(b1);
    const float l2 = __uint_as_float(b2);

    // gates: softmax + zero-expert-7 + renorm collapses to a sigmoid
    float g0, g1;
    if (i1 == 7)      { g0 = 0.f; g1 = 1.f; }
    else if (i2 == 7) { g0 = 1.f; g1 = 0.f; }
    else {
        const float p = 1.0f / (1.0f + __expf(-(l1 - l2) / stdv));
        g0 = p; g1 = 1.0f - p;
    }

    if (f == 0) out[(size_t)2 * t]             = g0;
    if (f == 1) out[(size_t)2 * t + 1]         = g1;
    if (f == 2) out[(size_t)2 * T + 2 * t]     = (float)i1;
    if (f == 3) out[(size_t)2 * T + 2 * t + 1] = (float)i2;
}

extern "C" void kernel_launch(void* const* d_in, const int* in_sizes, int n_in,
                              void* d_out, int out_size, void* d_ws, size_t ws_size,
                              hipStream_t stream) {
    const float* x  = (const float*)d_in[0];
    const float* wg = (const float*)d_in[1];
    const float* gm = (const float*)d_in[2];
    const float* gr = (const float*)d_in[3];
    float* ws = (float*)d_ws;                  // needs T/8*512*4 = 4 MB
    const int T = in_sizes[0] / DCONST;        // 16384

    const int gemm_blocks = (8 * (T / 32)) / 4;   // 1024
    router_gemm<<<gemm_blocks, 256, 0, stream>>>(x, wg, ws, T);

    const int epi_blocks = T / 32;                // 512
    router_epilogue<<<epi_blocks, 256, 0, stream>>>(ws, gm, gr, (float*)d_out, T);
}

// Round 6
// 205.448 us; speedup vs baseline: 2.5815x; 2.5815x over previous
//
#include <hip/hip_runtime.h>
#include <hip/hip_bf16.h>
#include <stdint.h>

// Router: logits = x @ wg^T + gr @ gm^T ; std-normalized softmax; top-2;
// zero expert 7; renormalize. Outputs flat: gates[T,2] | indices[T,2] (as
// float) | logits[T,8].  T=16384, D=2048, E=8.
//
// R6: single kernel, ZERO LDS, ZERO barriers, ZERO workspace, low pressure.
//  Evidence: R3 (26MB) and R5 (192MB WRITE_SIZE) prove register spill was
//  the hidden wall; R5's VGPR_Count=84 + straight-line code shows the
//  scheduler hoisting loads across batches. R6: 4 tokens/wave, acc[32],
//  wg read per-chunk from global (L2-hot, no staging), x ping-pong inside
//  a #pragma unroll 1 loop. Peak live ~111 VGPR vs cap 168 -> no spill.
//  Per iteration: wg loads issued BEFORE next-x loads so the in-order
//  vmcnt wait for wg leaves the x prefetch outstanding.

#define DCONST 2048

__device__ __forceinline__ unsigned long long shfl_xor_u64(unsigned long long v, int m) {
    int lo = __shfl_xor((int)(uint32_t)v, m, 64);
    int hi = __shfl_xor((int)(uint32_t)(v >> 32), m, 64);
    return ((unsigned long long)(uint32_t)hi << 32) | (unsigned long long)(uint32_t)lo;
}

__global__ __launch_bounds__(256, 3)
void router_kernel(const float* __restrict__ x,   // [T,2048]
                   const float* __restrict__ wg,  // [8,2048]
                   const float* __restrict__ gm,  // [8,8]
                   const float* __restrict__ gr,  // [T,8]
                   float* __restrict__ out,       // 2T gates | 2T idx | 8T logits
                   int T)
{
    const int wave = threadIdx.x >> 6;
    const int lane = threadIdx.x & 63;
    const int t0   = (blockIdx.x * 4 + wave) * 4;   // 4 tokens per wave

    const float* xp = x  + (size_t)t0 * DCONST + (lane << 2);
    const float* wp = wg + (lane << 2);

    float acc[32];
    #pragma unroll
    for (int v = 0; v < 32; ++v) acc[v] = 0.f;

    float4 xa[4], xb[4], w8[8];

    #define LOADX(buf, j)                                                     \
        { _Pragma("unroll")                                                   \
          for (int i = 0; i < 4; ++i)                                         \
              buf[i] = *(const float4*)(xp + (size_t)i * DCONST + (j) * 256); }

    #define LOADW(j)                                                          \
        { _Pragma("unroll")                                                   \
          for (int e = 0; e < 8; ++e)                                         \
              w8[e] = *(const float4*)(wp + (size_t)e * DCONST + (j) * 256); }

    #define FMA4(buf)                                                         \
        { _Pragma("unroll")                                                   \
          for (int i = 0; i < 4; ++i) {                                       \
              _Pragma("unroll")                                               \
              for (int e = 0; e < 8; ++e) {                                   \
                  float a = acc[i * 8 + e];                                   \
                  a += buf[i].x * w8[e].x;                                    \
                  a += buf[i].y * w8[e].y;                                    \
                  a += buf[i].z * w8[e].z;                                    \
                  a += buf[i].w * w8[e].w;                                    \
                  acc[i * 8 + e] = a;                                         \
              }                                                               \
          } }

    LOADX(xa, 0);
    #pragma unroll 1
    for (int j = 0; j < 8; j += 2) {
        LOADW(j);                       // wg chunk j (L2-hot)
        LOADX(xb, j + 1);               // x prefetch AFTER wg: wg-wait keeps it in flight
        FMA4(xa);
        LOADW(j + 1);
        if (j + 2 < 8) LOADX(xa, j + 2);
        FMA4(xb);
    }

    // ---- butterfly reduce-scatter over 32 values within each 32-lane half,
    // then xor-32 fold (halves cover disjoint column sets). All 64 lanes end
    // with value vv = lane&31 : token vv>>3, expert vv&7. (Verified in R5.)
    #pragma unroll
    for (int m = 1; m < 32; m <<= 1) {
        const bool up = (lane & m) != 0;
        #pragma unroll
        for (int v = 0; v < 32; v += 2 * m) {
            const float keep = up ? acc[v + m] : acc[v];
            const float send = up ? acc[v] : acc[v + m];
            const float got  = __shfl_xor(send, m, 64);
            acc[v] = keep + got;
        }
    }
    float logit = acc[0] + __shfl_xor(acc[0], 32, 64);

    const int vv = lane & 31;
    const int tt = vv >> 3;       // token 0..3
    const int f  = vv & 7;        // expert 0..7
    const int t  = t0 + tt;

    // ---- residual: logit += sum_e gr[t][e] * gm[f][e]
    const float4 ga = *(const float4*)(gr + (size_t)t * 8);
    const float4 gb = *(const float4*)(gr + (size_t)t * 8 + 4);
    const float4 ma = *(const float4*)(gm + f * 8);
    const float4 mb = *(const float4*)(gm + f * 8 + 4);
    logit += ga.x * ma.x + ga.y * ma.y + ga.z * ma.z + ga.w * ma.w
           + gb.x * mb.x + gb.y * mb.y + gb.z * mb.z + gb.w * mb.w;

    // logits output (offset 4T): lanes 0..31 cover the wave's 4 tokens
    if (lane < 32)
        out[(size_t)4 * T + (size_t)t0 * 8 + vv] = logit;

    // ---- stats over the 8-lane expert group (valid in both halves)
    float s = logit;
    s += __shfl_xor(s, 1, 64);
    s += __shfl_xor(s, 2, 64);
    s += __shfl_xor(s, 4, 64);
    const float mean = s * 0.125f;
    float d2 = (logit - mean) * (logit - mean);
    d2 += __shfl_xor(d2, 1, 64);
    d2 += __shfl_xor(d2, 2, 64);
    d2 += __shfl_xor(d2, 4, 64);
    const float stdv = sqrtf(d2 / 7.0f);    // ddof=1

    // ---- top-2 via order-preserving 64-bit keys; ties -> smaller index
    uint32_t ob = __float_as_uint(logit);
    ob = (ob & 0x80000000u) ? ~ob : (ob | 0x80000000u);
    unsigned long long k1 = ((unsigned long long)ob << 8) | (unsigned long long)(7 - f);
    unsigned long long k2 = 0ull;
    #pragma unroll
    for (int m = 1; m <= 4; m <<= 1) {
        const unsigned long long o1 = shfl_xor_u64(k1, m);
        const unsigned long long o2 = shfl_xor_u64(k2, m);
        const unsigned long long hi = k1 > o1 ? k1 : o1;
        const unsigned long long lo = k1 > o1 ? o1 : k1;
        const unsigned long long so = k2 > o2 ? k2 : o2;
        k1 = hi;
        k2 = lo > so ? lo : so;
    }
    const int i1 = 7 - (int)(k1 & 0xFFull);
    const int i2 = 7 - (int)(k2 & 0xFFull);
    uint32_t b1 = (uint32_t)(k1 >> 8), b2 = (uint32_t)(k2 >> 8);
    b1 = (b1 & 0x80000000u) ? (b1 ^ 0x80000000u) : ~b1;
    b2 = (b2 & 0x80000000u) ? (b2 ^ 0x80000000u) : ~b2;
    const float l1 = __uint_as_float(b1);
    const float l2 = __uint_as_float(b2);

    // gates: softmax + zero-expert-7 + renorm collapses to a sigmoid
    float g0, g1;
    if (i1 == 7)      { g0 = 0.f; g1 = 1.f; }
    else if (i2 == 7) { g0 = 1.f; g1 = 0.f; }
    else {
        const float p = 1.0f / (1.0f + __expf(-(l1 - l2) / stdv));
        g0 = p; g1 = 1.0f - p;
    }

    if (lane < 32) {
        if (f == 0) out[(size_t)2 * t]             = g0;
        if (f == 1) out[(size_t)2 * t + 1]         = g1;
        if (f == 2) out[(size_t)2 * T + 2 * t]     = (float)i1;
        if (f == 3) out[(size_t)2 * T + 2 * t + 1] = (float)i2;
    }
}

extern "C" void kernel_launch(void* const* d_in, const int* in_sizes, int n_in,
                              void* d_out, int out_size, void* d_ws, size_t ws_size,
                              hipStream_t stream) {
    const float* x  = (const float*)d_in[0];
    const float* wg = (const float*)d_in[1];
    const float* gm = (const float*)d_in[2];
    const float* gr = (const float*)d_in[3];
    const int T = in_sizes[0] / DCONST;        // 16384
    const int blocks = T / 16;                 // 1024 (4 waves x 4 tokens)
    router_kernel<<<blocks, 256, 0, stream>>>(x, wg, gm, gr, (float*)d_out, T);
}

// Round 7
// 189.463 us; speedup vs baseline: 2.7993x; 1.0844x over previous
//
#include <hip/hip_runtime.h>
#include <hip/hip_bf16.h>
#include <stdint.h>

// Router: logits = x @ wg^T + gr @ gm^T ; std-normalized softmax; top-2;
// zero expert 7; renormalize. Outputs flat: gates[T,2] | indices[T,2] (as
// float) | logits[T,8].  T=16384, D=2048, E=8.
//
// R7 = R4's split-K structure + NON-TEMPORAL x loads + big reg cap.
//  Evidence: R1/R2/R4/R6 (four different structures, 8-12 waves/CU) all
//  plateau at ~2.2 TB/s x-stream -> consistent with a per-CU L1 miss-line
//  (MSHR) limit ~64 lines: 64*64B/375ns ~= 2.8 TB/s device-wide,
//  independent of occupancy. Fix: nt loads bypass L1 allocation for the
//  read-once x stream (wg stays cacheable in regs/L2).
//  Kernel 1: wave owns (column-group of 256 cols, 32 tokens); wg slice in
//    32 VGPRs loaded once; NO LDS, NO barriers. Per 8-token batch: 8x 1KB
//    nt x-loads (ping-pong), 256 fmacs, 64-value butterfly reduce-scatter,
//    256B partial store to ws (normal store -> L2-hot for kernel 2).
//  Kernel 2: lane sums 8 column-group partials, then proven epilogue.

#define DCONST 2048
#define TOK_PER_BATCH 8
#define BATCHES 4

typedef float f32x4 __attribute__((ext_vector_type(4)));

__device__ __forceinline__ unsigned long long shfl_xor_u64(unsigned long long v, int m) {
    int lo = __shfl_xor((int)(uint32_t)v, m, 64);
    int hi = __shfl_xor((int)(uint32_t)(v >> 32), m, 64);
    return ((unsigned long long)(uint32_t)hi << 32) | (unsigned long long)(uint32_t)lo;
}

// ---------------- Kernel 1: split-K partial GEMM ----------------
__global__ __launch_bounds__(256, 2)
void router_gemm(const float* __restrict__ x,   // [T,2048]
                 const float* __restrict__ wg,  // [8,2048]
                 float* __restrict__ ws,        // [T/8][8][64] partials
                 int T)
{
    const int wave  = threadIdx.x >> 6;
    const int lane  = threadIdx.x & 63;
    const int W     = blockIdx.x * 4 + wave;
    const int g     = W & 7;                 // column group (256 cols)
    const int tbase = (W >> 3) * 32;         // first of 32 tokens

    // wg slice for this lane's 4 columns, all 8 experts: 32 VGPRs, once.
    const float* wgp = wg + g * 256 + (lane << 2);
    f32x4 w8[8];
    #pragma unroll
    for (int e = 0; e < 8; ++e)
        w8[e] = *(const f32x4*)(wgp + (size_t)e * DCONST);

    const float* xp = x + (size_t)tbase * DCONST + g * 256 + (lane << 2);

    f32x4 xa[4], xb[4];

    #define LOADH(buf, trow)                                                  \
        { _Pragma("unroll")                                                   \
          for (int i = 0; i < 4; ++i)                                         \
              buf[i] = __builtin_nontemporal_load(                            \
                  (const f32x4*)(xp + (size_t)((trow) + i) * DCONST)); }

    #define FMAH(buf, tloc0)                                                  \
        { _Pragma("unroll")                                                   \
          for (int i = 0; i < 4; ++i) {                                       \
              _Pragma("unroll")                                               \
              for (int e = 0; e < 8; ++e) {                                   \
                  float a = acc[((tloc0) + i) * 8 + e];                       \
                  a += buf[i].x * w8[e].x;                                    \
                  a += buf[i].y * w8[e].y;                                    \
                  a += buf[i].z * w8[e].z;                                    \
                  a += buf[i].w * w8[e].w;                                    \
                  acc[((tloc0) + i) * 8 + e] = a;                             \
              }                                                               \
          } }

    LOADH(xa, 0);
    LOADH(xb, 4);

    #pragma unroll 1
    for (int b = 0; b < BATCHES; ++b) {
        float acc[64];
        #pragma unroll
        for (int v = 0; v < 64; ++v) acc[v] = 0.f;

        FMAH(xa, 0);                       // tokens b*8 + 0..3
        if (b < BATCHES - 1) LOADH(xa, (b + 1) * 8);
        FMAH(xb, 4);                       // tokens b*8 + 4..7
        if (b < BATCHES - 1) LOADH(xb, (b + 1) * 8 + 4);

        // butterfly reduce-scatter: lane l ends with value l = tloc*8+e
        #pragma unroll
        for (int m = 1; m < 64; m <<= 1) {
            const bool up = (lane & m) != 0;
            #pragma unroll
            for (int v = 0; v < 64; v += 2 * m) {
                const float keep = up ? acc[v + m] : acc[v];
                const float send = up ? acc[v] : acc[v + m];
                const float got  = __shfl_xor(send, m, 64);
                acc[v] = keep + got;
            }
        }

        const int tb = (tbase + b * TOK_PER_BATCH) >> 3;   // token-batch id
        ws[(size_t)tb * 512 + g * 64 + lane] = acc[0];
    }
}

// ---------------- Kernel 2: reduce + epilogue ----------------
__global__ __launch_bounds__(256)
void router_epilogue(const float* __restrict__ ws,  // [T/8][8][64]
                     const float* __restrict__ gm,  // [8,8]
                     const float* __restrict__ gr,  // [T,8]
                     float* __restrict__ out,       // 2T gates | 2T idx | 8T logits
                     int T)
{
    const int wave = threadIdx.x >> 6;
    const int lane = threadIdx.x & 63;
    const int tb   = blockIdx.x * 4 + wave;    // [0, T/8)
    const int t0   = tb * 8;

    float logit = 0.f;
    #pragma unroll
    for (int g = 0; g < 8; ++g)
        logit += ws[(size_t)tb * 512 + g * 64 + lane];

    const int tt = lane >> 3;
    const int f  = lane & 7;
    const int t  = t0 + tt;

    // residual: logit += sum_e gr[t][e] * gm[f][e]
    const float4 ga = *(const float4*)(gr + (size_t)t * 8);
    const float4 gb = *(const float4*)(gr + (size_t)t * 8 + 4);
    const float4 ma = *(const float4*)(gm + f * 8);
    const float4 mb = *(const float4*)(gm + f * 8 + 4);
    logit += ga.x * ma.x + ga.y * ma.y + ga.z * ma.z + ga.w * ma.w
           + gb.x * mb.x + gb.y * mb.y + gb.z * mb.z + gb.w * mb.w;

    // logits output (offset 4T), contiguous per wave
    out[(size_t)4 * T + (size_t)t0 * 8 + lane] = logit;

    // stats over the 8-lane expert group
    float s = logit;
    s += __shfl_xor(s, 1, 64);
    s += __shfl_xor(s, 2, 64);
    s += __shfl_xor(s, 4, 64);
    const float mean = s * 0.125f;
    float d2 = (logit - mean) * (logit - mean);
    d2 += __shfl_xor(d2, 1, 64);
    d2 += __shfl_xor(d2, 2, 64);
    d2 += __shfl_xor(d2, 4, 64);
    const float stdv = sqrtf(d2 / 7.0f);    // ddof=1

    // top-2 via order-preserving 64-bit keys; ties -> smaller index
    uint32_t ob = __float_as_uint(logit);
    ob = (ob & 0x80000000u) ? ~ob : (ob | 0x80000000u);
    unsigned long long k1 = ((unsigned long long)ob << 8) | (unsigned long long)(7 - f);
    unsigned long long k2 = 0ull;
    #pragma unroll
    for (int m = 1; m <= 4; m <<= 1) {
        const unsigned long long o1 = shfl_xor_u64(k1, m);
        const unsigned long long o2 = shfl_xor_u64(k2, m);
        const unsigned long long hi = k1 > o1 ? k1 : o1;
        const unsigned long long lo = k1 > o1 ? o1 : k1;
        const unsigned long long so = k2 > o2 ? k2 : o2;
        k1 = hi;
        k2 = lo > so ? lo : so;
    }
    const int i1 = 7 - (int)(k1 & 0xFFull);
    const int i2 = 7 - (int)(k2 & 0xFFull);
    uint32_t b1 = (uint32_t)(k1 >> 8), b2 = (uint32_t)(k2 >> 8);
    b1 = (b1 & 0x80000000u) ? (b1 ^ 0x80000000u) : ~b1;
    b2 = (b2 & 0x80000000u) ? (b2 ^ 0x80000000u) : ~b2;
    const float l1 = __uint_as_float(b1);
    const float l2 = __uint_as_float(b2);

    // gates: softmax + zero-expert-7 + renorm collapses to a sigmoid
    float g0, g1;
    if (i1 == 7)      { g0 = 0.f; g1 = 1.f; }
    else if (i2 == 7) { g0 = 1.f; g1 = 0.f; }
    else {
        const float p = 1.0f / (1.0f + __expf(-(l1 - l2) / stdv));
        g0 = p; g1 = 1.0f - p;
    }

    if (f == 0) out[(size_t)2 * t]             = g0;
    if (f == 1) out[(size_t)2 * t + 1]         = g1;
    if (f == 2) out[(size_t)2 * T + 2 * t]     = (float)i1;
    if (f == 3) out[(size_t)2 * T + 2 * t + 1] = (float)i2;
}

extern "C" void kernel_launch(void* const* d_in, const int* in_sizes, int n_in,
                              void* d_out, int out_size, void* d_ws, size_t ws_size,
                              hipStream_t stream) {
    const float* x  = (const float*)d_in[0];
    const float* wg = (const float*)d_in[1];
    const float* gm = (const float*)d_in[2];
    const float* gr = (const float*)d_in[3];
    float* ws = (float*)d_ws;                  // needs T/8*512*4 = 4 MB
    const int T = in_sizes[0] / DCONST;        // 16384

    const int gemm_blocks = (8 * (T / 32)) / 4;   // 1024
    router_gemm<<<gemm_blocks, 256, 0, stream>>>(x, wg, ws, T);

    const int epi_blocks = T / 32;                // 512
    router_epilogue<<<epi_blocks, 256, 0, stream>>>(ws, gm, gr, (float*)d_out, T);
}